// Round 5
// baseline (635.897 us; speedup 1.0000x reference)
//
#include <hip/hip_runtime.h>
#include <hip/hip_bf16.h>

typedef short short8 __attribute__((ext_vector_type(8)));
typedef float f32x4 __attribute__((ext_vector_type(4)));

#define T_ 512
#define B_ 1024
#define D_ 128
#define H_ 64
#define A_ 18
#define TB_ (T_*B_)

// ws layout (ushort units): [x_actor | x_critic | bf16 weights]
// x is PLAIN row-major [T][B][H]. scan overwrites x[t] with h[t] (row-major).
#define XELEMS (TB_*H_)          // 33554432 per branch
#define WBASE  (2*XELEMS)
#define WBR    38912             // per-branch weight elems
#define W1OFF  0
#define W2OFF  8192
#define WIHOFF 12288
#define WHHOFF 24576
#define WHDOFF 36864

// out layout (floats): logits | values | actor_state | critic_state
#define LOGN  (TB_*A_)           // 9437184
#define VOFF_ LOGN
#define SOFF_ (LOGN + TB_)       // 9961472

#define S1_ (-1.4426950408889634f)   // -log2(e)   (r,z gates)
#define S2_ (-2.885390081777927f)    // -2*log2(e) (n gate)

__device__ __forceinline__ ushort f2bf(float f) {
  __hip_bfloat16 h = __float2bfloat16(f);
  return __builtin_bit_cast(ushort, h);
}
__device__ __forceinline__ uint cvt_pk_bf16(float lo, float hi) {
  uint r;
  asm("v_cvt_pk_bf16_f32 %0, %1, %2" : "=v"(r) : "v"(lo), "v"(hi));
  return r;
}
__device__ __forceinline__ f32x4 mfma16(short8 a, short8 b, f32x4 c) {
  return __builtin_amdgcn_mfma_f32_16x16x32_bf16(a, b, c, 0, 0, 0);
}

__global__ __launch_bounds__(256) void prep_kernel(
    const float* aW1, const float* aW2, const float* aWih, const float* aWhh, const float* aWl,
    const float* cW1, const float* cW2, const float* cWih, const float* cWhh, const float* cWv,
    ushort* wts) {
  int idx = blockIdx.x * 256 + threadIdx.x;
  if (idx >= 2*WBR) return;
  int br = idx / WBR, off = idx % WBR;
  float v;
  if      (off < W2OFF)  v = (br ? cW1  : aW1 )[off];
  else if (off < WIHOFF) v = (br ? cW2  : aW2 )[off - W2OFF];
  else if (off < WHHOFF) {
    int rel = off - WIHOFF;
    v = (br ? cWih : aWih)[rel];
    v *= (rel < 128*H_) ? S1_ : S2_;      // fold gate logistic scales
  }
  else if (off < WHDOFF) {
    int rel = off - WHHOFF;
    v = (br ? cWhh : aWhh)[rel];
    v *= (rel < 128*H_) ? S1_ : S2_;
  }
  else {
    int t = off - WHDOFF;
    if (br == 0) v = (t < A_*H_) ? aWl[t] : 0.f;
    else         v = (t < H_)    ? cWv[t] : 0.f;
  }
  wts[WBASE + idx] = f2bf(v);
}

// ---------------- phase 1: fused MLP, barrier-free, x -> ws (bf16, PLAIN row-major) ---
__global__ __launch_bounds__(256) void mlp_kernel(
    const float* __restrict__ obs, const ushort* __restrict__ wts,
    const float* __restrict__ ab1, const float* __restrict__ ab2,
    const float* __restrict__ cb1, const float* __restrict__ cb2,
    ushort* __restrict__ xout) {
  __shared__ __align__(16) ushort obsb[4][16 * D_];   // per-wave 4KB staged obs (bf16)
  __shared__ __align__(16) ushort htmp[4][16 * H_];   // per-wave 2KB, wave-local only
  const int tid = threadIdx.x;
  const int l = tid & 63, w = tid >> 6;
  const int lr = l & 15, lg = l >> 4;
  const int key = lr & 7;
  const long r0 = (long)blockIdx.x * 64;
  const f32x4 fzero = {0.f, 0.f, 0.f, 0.f};

  // stage this wave's 16 obs rows: fully-coalesced f32 loads -> cvt -> swizzled LDS
  {
    const float* src = obs + (r0 + (long)w * 16) * D_;
    #pragma unroll
    for (int i = 0; i < 8; ++i) {
      int ri = i * 2 + (l >> 5);          // row 0..15
      int cq = (l & 31) * 4;              // f32 col
      float4 v = *(const float4*)(src + ri * D_ + cq);
      uint lo = cvt_pk_bf16(v.x, v.y);
      uint hi = cvt_pk_bf16(v.z, v.w);
      int ch = (l & 31) >> 1;             // 16B chunk 0..15
      int chs = (ch & 8) | ((ch & 7) ^ (ri & 7));
      *(uint2*)(&obsb[w][ri * D_ + chs * 8 + (l & 1) * 4]) = uint2{lo, hi};
    }
  }
  // A-fragments from staged LDS (wave-local; compiler inserts lgkm waits)
  short8 af[4];
  #pragma unroll
  for (int ks = 0; ks < 4; ++ks) {
    int ch = ks * 4 + lg;
    int chs = (ch & 8) | ((ch & 7) ^ (lr & 7));
    af[ks] = *(const short8*)(&obsb[w][lr * D_ + chs * 8]);
  }

  #pragma unroll 1
  for (int br = 0; br < 2; ++br) {
    const ushort* wb = wts + WBASE + br * WBR;
    const float* b1 = br ? cb1 : ab1;
    const float* b2 = br ? cb2 : ab2;

    // ---- layer 1: [16,128] @ [128,64]
    f32x4 acc[4];
    #pragma unroll
    for (int nt = 0; nt < 4; ++nt) acc[nt] = fzero;
    #pragma unroll
    for (int ks = 0; ks < 4; ++ks) {
      #pragma unroll
      for (int nt = 0; nt < 4; ++nt) {
        int n = nt * 16 + lr;
        short8 b = *(const short8*)(wb + W1OFF + n * D_ + ks * 32 + lg * 8);
        acc[nt] = mfma16(af[ks], b, acc[nt]);
      }
    }
    // bias+relu -> htmp[w] (16B-unit swizzle, key=row&7), wave-local
    #pragma unroll
    for (int nt = 0; nt < 4; ++nt) {
      int coln = nt * 16 + lr;
      float bias = b1[coln];
      #pragma unroll
      for (int j = 0; j < 4; ++j) {
        int rw = lg * 4 + j;
        float v = fmaxf(acc[nt][j] + bias, 0.f);
        int idx = rw * H_ + ((((coln >> 3) ^ (rw & 7))) << 3) + (coln & 7);
        htmp[w][idx] = f2bf(v);
      }
    }
    // ---- layer 2: [16,64] @ [64,64]  (wave-local ds round-trip, no barrier)
    short8 a2[2];
    #pragma unroll
    for (int ks = 0; ks < 2; ++ks) {
      int c = ks * 4 + lg;
      a2[ks] = *(const short8*)(&htmp[w][lr * H_ + ((c ^ key) << 3)]);
    }
    f32x4 acc2[4];
    #pragma unroll
    for (int nt = 0; nt < 4; ++nt) acc2[nt] = fzero;
    #pragma unroll
    for (int ks = 0; ks < 2; ++ks) {
      #pragma unroll
      for (int nt = 0; nt < 4; ++nt) {
        int n = nt * 16 + lr;
        short8 b = *(const short8*)(wb + W2OFF + n * H_ + ks * 32 + lg * 8);
        acc2[nt] = mfma16(a2[ks], b, acc2[nt]);
      }
    }
    #pragma unroll
    for (int nt = 0; nt < 4; ++nt) {
      int coln = nt * 16 + lr;
      float bias = b2[coln];
      #pragma unroll
      for (int j = 0; j < 4; ++j) {
        int rw = lg * 4 + j;
        float v = fmaxf(acc2[nt][j] + bias, 0.f);
        int idx = rw * H_ + ((((coln >> 3) ^ (rw & 7))) << 3) + (coln & 7);
        htmp[w][idx] = f2bf(v);
      }
    }
    // de-swizzling copy: htmp[w] -> global x, PLAIN row-major
    {
      ushort* dp = xout + (size_t)br * XELEMS + (size_t)(r0 + w * 16) * H_;
      #pragma unroll
      for (int i = 0; i < 2; ++i) {
        int id = l + i * 64;          // 128 chunks of 16B
        int rr = id >> 3, cc = id & 7;
        uint4 v = *(const uint4*)(&htmp[w][rr * H_ + ((cc ^ (rr & 7)) << 3)]);
        *(uint4*)(dp + rr * H_ + (cc << 3)) = v;
      }
    }
  }
}

// ---------------- phase 2: dual GRU scan (actor+critic chains share each wave) --------
__global__ __launch_bounds__(256, 1) void scan_kernel(
    const ushort* __restrict__ wts,     // ws + WBASE region
    const ushort* __restrict__ xin,     // ws x region (load-only view)
    ushort* __restrict__ hist,          // ws x region (store-only view; t-disjoint)
    const float* __restrict__ dones,
    const float* __restrict__ astate, const float* __restrict__ cstate,
    const float* __restrict__ abih, const float* __restrict__ abhh,
    const float* __restrict__ cbih, const float* __restrict__ cbhh,
    float* __restrict__ out) {
  __shared__ __align__(16) ushort hbufA[2][16 * H_];  // h^T tiles, 16B-unit swizzled
  __shared__ __align__(16) ushort hbufC[2][16 * H_];
  __shared__ __align__(8)  ushort dl16[T_ * 16];      // done flags (0/1), 16KB, shared
  const int tid = threadIdx.x;
  const int l = tid & 63, w = tid >> 6;
  const int lr = l & 15, lg = l >> 4;
  const int b0 = blockIdx.x * 16;
  const f32x4 fzero = {0.f, 0.f, 0.f, 0.f};

  const ushort* wbA = wts;
  const ushort* wbC = wts + WBR;
  const ushort* xpA = xin;
  const ushort* xpC = xin + (size_t)XELEMS;
  ushort* hpA = hist;
  ushort* hpC = hist + (size_t)XELEMS;

  // dones -> LDS flags (one-time)
  #pragma unroll
  for (int i = 0; i < 8; ++i) {
    int s = tid + i * 256;              // 2048 float4 slots
    int t = s >> 2, p = s & 3;
    float4 v = *(const float4*)(dones + (size_t)t * B_ + b0 + p * 4);
    uint lo = (v.x != 0.f ? 1u : 0u) | ((v.y != 0.f ? 1u : 0u) << 16);
    uint hi = (v.z != 0.f ? 1u : 0u) | ((v.w != 0.f ? 1u : 0u) << 16);
    *(uint2*)(&dl16[t * 16 + p * 4]) = uint2{lo, hi};
  }

  // persistent weight A-fragments (row = gate-col, k = h-col), both branches
  short8 ihA[3][2], hhA[3][2], ihC[3][2], hhC[3][2];
  #pragma unroll
  for (int g = 0; g < 3; ++g) {
    int n = g * 64 + w * 16 + lr;
    #pragma unroll
    for (int ks = 0; ks < 2; ++ks) {
      ihA[g][ks] = *(const short8*)(wbA + WIHOFF + n * H_ + ks * 32 + lg * 8);
      hhA[g][ks] = *(const short8*)(wbA + WHHOFF + n * H_ + ks * 32 + lg * 8);
      ihC[g][ks] = *(const short8*)(wbC + WIHOFF + n * H_ + ks * 32 + lg * 8);
      hhC[g][ks] = *(const short8*)(wbC + WHHOFF + n * H_ + ks * 32 + lg * 8);
    }
  }

  // biases for this lane's 4 gate-cols (scaled to match prescaled weights)
  const int o4 = w * 16 + lg * 4;
  f32x4 bsA0, bsA1, bnA, bhA, bsC0, bsC1, bnC, bhC;
  #pragma unroll
  for (int q = 0; q < 2; ++q) {
    const float* bi = q ? cbih : abih;
    const float* bh = q ? cbhh : abhh;
    float4 a0 = *(const float4*)(bi + o4),       h0v = *(const float4*)(bh + o4);
    float4 a1 = *(const float4*)(bi + 64 + o4),  h1v = *(const float4*)(bh + 64 + o4);
    float4 a2 = *(const float4*)(bi + 128 + o4), h2v = *(const float4*)(bh + 128 + o4);
    f32x4 s0, s1, nv, hv;
    s0[0]=S1_*(a0.x+h0v.x); s0[1]=S1_*(a0.y+h0v.y); s0[2]=S1_*(a0.z+h0v.z); s0[3]=S1_*(a0.w+h0v.w);
    s1[0]=S1_*(a1.x+h1v.x); s1[1]=S1_*(a1.y+h1v.y); s1[2]=S1_*(a1.z+h1v.z); s1[3]=S1_*(a1.w+h1v.w);
    nv[0]=S2_*a2.x; nv[1]=S2_*a2.y; nv[2]=S2_*a2.z; nv[3]=S2_*a2.w;
    hv[0]=S2_*h2v.x; hv[1]=S2_*h2v.y; hv[2]=S2_*h2v.z; hv[3]=S2_*h2v.w;
    if (q) { bsC0=s0; bsC1=s1; bnC=nv; bhC=hv; } else { bsA0=s0; bsA1=s1; bnA=nv; bhA=hv; }
  }

  // hbuf addressing (ushort units). write: 8B half-unit; read: 16B unit, XOR key lr&7
  const int myW = lr * H_ + (((w * 2 + (lg >> 1)) ^ (lr & 7)) << 3) + (lg & 1) * 4;
  const int rdA = lr * H_ + (((0 + lg) ^ (lr & 7)) << 3);
  const int rdB = lr * H_ + (((4 + lg) ^ (lr & 7)) << 3);

  // h init: lane holds (batch b0+lr, cols o4..o4+3), fp32, both branches
  float hA_old[4], hC_old[4];
  {
    float4 ha = *(const float4*)(astate + (size_t)(b0 + lr) * H_ + o4);
    float4 hc = *(const float4*)(cstate + (size_t)(b0 + lr) * H_ + o4);
    bool rs0 = (dones[b0 + lr] != 0.f);
    hA_old[0] = rs0 ? 0.f : ha.x; hA_old[1] = rs0 ? 0.f : ha.y;
    hA_old[2] = rs0 ? 0.f : ha.z; hA_old[3] = rs0 ? 0.f : ha.w;
    hC_old[0] = rs0 ? 0.f : hc.x; hC_old[1] = rs0 ? 0.f : hc.y;
    hC_old[2] = rs0 ? 0.f : hc.z; hC_old[3] = rs0 ? 0.f : hc.w;
    uint2 hv;
    hv.x = cvt_pk_bf16(hA_old[0], hA_old[1]);
    hv.y = cvt_pk_bf16(hA_old[2], hA_old[3]);
    *(uint2*)(&hbufA[0][myW]) = hv;
    hv.x = cvt_pk_bf16(hC_old[0], hC_old[1]);
    hv.y = cvt_pk_bf16(hC_old[2], hC_old[3]);
    *(uint2*)(&hbufC[0][myW]) = hv;
  }

  __syncthreads();   // dl16 + hbuf[0] visible

  auto loadx = [&](const ushort* xp2, int t, short8 (&f)[2]) {
    const ushort* p = xp2 + ((size_t)t * B_ + b0 + lr) * H_;
    f[0] = *(const short8*)(p + lg * 8);
    f[1] = *(const short8*)(p + 32 + lg * 8);
  };

  short8 bufA0[2], bufA1[2], bufC0[2], bufC1[2];
  loadx(xpA, 0, bufA0); loadx(xpA, 1, bufA1);
  loadx(xpC, 0, bufC0); loadx(xpC, 1, bufC1);

  // one branch, one step. reads hb[cur], writes hb[cur^1]; prefetch t+2 into xb.
  auto brstep = [&](int t, int cur, short8 (&xb)[2],
                    const short8 (&ihW)[3][2], const short8 (&hhW)[3][2],
                    ushort (*hb)[16 * H_],
                    const f32x4& bs0, const f32x4& bs1, const f32x4& binv, const f32x4& bhnv,
                    float (&h_old)[4], const ushort* xp2, ushort* hp2) {
    short8 hf0 = *(const short8*)(&hb[cur][rdA]);
    short8 hf1 = *(const short8*)(&hb[cur][rdB]);
    int tn = t + 1;
    ushort dn = dl16[((tn < T_) ? tn : 0) * 16 + lr];
    bool rs = (tn < T_) && (dn != 0);

    f32x4 gi0 = fzero, gi1 = fzero, gi2 = fzero;
    gi0 = mfma16(ihW[0][0], xb[0], gi0); gi0 = mfma16(ihW[0][1], xb[1], gi0);
    gi1 = mfma16(ihW[1][0], xb[0], gi1); gi1 = mfma16(ihW[1][1], xb[1], gi1);
    gi2 = mfma16(ihW[2][0], xb[0], gi2); gi2 = mfma16(ihW[2][1], xb[1], gi2);
    f32x4 gh0 = fzero, gh1 = fzero, gh2 = fzero;
    gh0 = mfma16(hhW[0][0], hf0, gh0); gh0 = mfma16(hhW[0][1], hf1, gh0);
    gh1 = mfma16(hhW[1][0], hf0, gh1); gh1 = mfma16(hhW[1][1], hf1, gh1);
    gh2 = mfma16(hhW[2][0], hf0, gh2); gh2 = mfma16(hhW[2][1], hf1, gh2);

    // prefetch t+2 into the consumed buffer
    int tp = (t + 2 < T_) ? t + 2 : T_ - 1;
    loadx(xp2, tp, xb);

    float hn[4];
    #pragma unroll
    for (int j = 0; j < 4; ++j) {
      float sr = gi0[j] + gh0[j] + bs0[j];
      float rr = __builtin_amdgcn_rcpf(1.f + __builtin_amdgcn_exp2f(sr));
      float sz = gi1[j] + gh1[j] + bs1[j];
      float zz = __builtin_amdgcn_rcpf(1.f + __builtin_amdgcn_exp2f(sz));
      float tg = gh2[j] + bhnv[j];
      float sn = fmaf(rr, tg, gi2[j] + binv[j]);
      float qq = __builtin_amdgcn_rcpf(1.f + __builtin_amdgcn_exp2f(sn));
      float nn = fmaf(2.f, qq, -1.f);
      hn[j] = fmaf(zz, h_old[j] - nn, nn);
    }
    uint2 hv;
    hv.x = cvt_pk_bf16(hn[0], hn[1]);
    hv.y = cvt_pk_bf16(hn[2], hn[3]);
    *(uint2*)(hp2 + ((size_t)t * B_ + b0 + lr) * H_ + o4) = hv;   // history (pre-reset)
    uint2 hz;
    hz.x = rs ? 0u : hv.x;
    hz.y = rs ? 0u : hv.y;
    h_old[0] = rs ? 0.f : hn[0]; h_old[1] = rs ? 0.f : hn[1];
    h_old[2] = rs ? 0.f : hn[2]; h_old[3] = rs ? 0.f : hn[3];
    *(uint2*)(&hb[cur ^ 1][myW]) = hz;
  };

  int cur = 0;
  for (int it = 0; it < T_ / 2; ++it) {
    int t0 = 2 * it, t1 = 2 * it + 1;
    brstep(t0, cur, bufA0, ihA, hhA, hbufA, bsA0, bsA1, bnA, bhA, hA_old, xpA, hpA);
    brstep(t0, cur, bufC0, ihC, hhC, hbufC, bsC0, bsC1, bnC, bhC, hC_old, xpC, hpC);
    asm volatile("s_waitcnt lgkmcnt(0)" ::: "memory");
    __builtin_amdgcn_s_barrier();
    cur ^= 1;
    brstep(t1, cur, bufA1, ihA, hhA, hbufA, bsA0, bsA1, bnA, bhA, hA_old, xpA, hpA);
    brstep(t1, cur, bufC1, ihC, hhC, hbufC, bsC0, bsC1, bnC, bhC, hC_old, xpC, hpC);
    asm volatile("s_waitcnt lgkmcnt(0)" ::: "memory");
    __builtin_amdgcn_s_barrier();
    cur ^= 1;
  }

  // final states (fp32, post step 511; no reset applied on last step)
  float4 fa = {hA_old[0], hA_old[1], hA_old[2], hA_old[3]};
  float4 fc = {hC_old[0], hC_old[1], hC_old[2], hC_old[3]};
  *(float4*)(out + SOFF_ + (size_t)(b0 + lr) * H_ + o4) = fa;
  *(float4*)(out + SOFF_ + (size_t)B_ * H_ + (size_t)(b0 + lr) * H_ + o4) = fc;
}

// ---------------- phase 3: heads (logits + values) from row-major h history -----------
__global__ __launch_bounds__(256) void head_kernel(
    const ushort* __restrict__ ws,
    const float* __restrict__ abl, const float* __restrict__ cbv,
    float* __restrict__ out) {
  const int tid = threadIdx.x;
  const int l = tid & 63, w = tid >> 6;
  const int lr = l & 15, lg = l >> 4;
  const long r0 = (long)blockIdx.x * 64 + w * 16;   // TB-row base for this wave
  const f32x4 fzero = {0.f, 0.f, 0.f, 0.f};

  const ushort* hA = ws + r0 * H_;
  const ushort* hC = ws + XELEMS + r0 * H_;
  short8 aA[2], aC[2];
  #pragma unroll
  for (int ks = 0; ks < 2; ++ks) {
    aA[ks] = *(const short8*)(hA + lr * H_ + ks * 32 + lg * 8);
    aC[ks] = *(const short8*)(hC + lr * H_ + ks * 32 + lg * 8);
  }
  // logits: [16,64]@[64,32] (Wl zero-padded to 32 rows)
  const ushort* wbA = ws + WBASE + WHDOFF;
  const ushort* wbC = ws + WBASE + WBR + WHDOFF;
  f32x4 acc[2];
  acc[0] = fzero; acc[1] = fzero;
  #pragma unroll
  for (int nt = 0; nt < 2; ++nt) {
    int n = nt * 16 + lr;
    #pragma unroll
    for (int ks = 0; ks < 2; ++ks) {
      short8 b = *(const short8*)(wbA + n * H_ + ks * 32 + lg * 8);
      acc[nt] = mfma16(aA[ks], b, acc[nt]);
    }
  }
  // values: [16,64]@[64,16] (only n==0 nonzero)
  f32x4 vacc = fzero;
  {
    int n = lr;
    #pragma unroll
    for (int ks = 0; ks < 2; ++ks) {
      short8 b = *(const short8*)(wbC + n * H_ + ks * 32 + lg * 8);
      vacc = mfma16(aC[ks], b, vacc);
    }
  }
  // stores
  #pragma unroll
  for (int nt = 0; nt < 2; ++nt) {
    int n = nt * 16 + lr;
    if (n < A_) {
      float bias = abl[n];
      #pragma unroll
      for (int j = 0; j < 4; ++j)
        out[(r0 + lg * 4 + j) * A_ + n] = acc[nt][j] + bias;
    }
  }
  if (lr == 0) {
    float bias = cbv[0];
    #pragma unroll
    for (int j = 0; j < 4; ++j)
      out[VOFF_ + r0 + lg * 4 + j] = vacc[j] + bias;
  }
}

extern "C" void kernel_launch(void* const* d_in, const int* in_sizes, int n_in,
                              void* d_out, int out_size, void* d_ws, size_t ws_size,
                              hipStream_t stream) {
  const float* obs    = (const float*)d_in[0];
  const float* dones  = (const float*)d_in[1];
  const float* astate = (const float*)d_in[2];
  const float* cstate = (const float*)d_in[3];
  const float* aW1  = (const float*)d_in[4];
  const float* ab1  = (const float*)d_in[5];
  const float* aW2  = (const float*)d_in[6];
  const float* ab2  = (const float*)d_in[7];
  const float* aWih = (const float*)d_in[8];
  const float* aWhh = (const float*)d_in[9];
  const float* abih = (const float*)d_in[10];
  const float* abhh = (const float*)d_in[11];
  const float* aWl  = (const float*)d_in[12];
  const float* abl  = (const float*)d_in[13];
  const float* cW1  = (const float*)d_in[14];
  const float* cb1  = (const float*)d_in[15];
  const float* cW2  = (const float*)d_in[16];
  const float* cb2  = (const float*)d_in[17];
  const float* cWih = (const float*)d_in[18];
  const float* cWhh = (const float*)d_in[19];
  const float* cbih = (const float*)d_in[20];
  const float* cbhh = (const float*)d_in[21];
  const float* cWv  = (const float*)d_in[22];
  const float* cbv  = (const float*)d_in[23];
  ushort* ws = (ushort*)d_ws;
  float* out = (float*)d_out;

  const size_t need = ((size_t)2 * XELEMS + 2 * WBR) * 2;
  if (ws_size < need) {
    hipMemsetAsync(d_out, 0x7F, 16, stream);
    return;
  }

  hipLaunchKernelGGL(prep_kernel, dim3(304), dim3(256), 0, stream,
                     aW1, aW2, aWih, aWhh, aWl, cW1, cW2, cWih, cWhh, cWv, ws);
  hipLaunchKernelGGL(mlp_kernel, dim3(TB_ / 64), dim3(256), 0, stream,
                     obs, ws, ab1, ab2, cb1, cb2, ws);
  hipLaunchKernelGGL(scan_kernel, dim3(64), dim3(256), 0, stream,
                     ws + WBASE, ws, ws, dones, astate, cstate,
                     abih, abhh, cbih, cbhh, out);
  hipLaunchKernelGGL(head_kernel, dim3(TB_ / 64), dim3(256), 0, stream,
                     ws, abl, cbv, out);
}

// Round 6
// 610.825 us; speedup vs baseline: 1.0410x; 1.0410x over previous
//
#include <hip/hip_runtime.h>
#include <hip/hip_bf16.h>

typedef short short8 __attribute__((ext_vector_type(8)));
typedef float f32x4 __attribute__((ext_vector_type(4)));

#define T_ 512
#define B_ 1024
#define D_ 128
#define H_ 64
#define A_ 18
#define TB_ (T_*B_)

// ws layout (ushort units): [x_actor | x_critic | bf16 weights]
// x is PLAIN row-major [T][B][H]. scan overwrites x[t] with h[t] (row-major).
#define XELEMS (TB_*H_)          // 33554432 per branch
#define WBASE  (2*XELEMS)
#define WBR    38912             // per-branch weight elems
#define W1OFF  0
#define W2OFF  8192
#define WIHOFF 12288
#define WHHOFF 24576
#define WHDOFF 36864

// out layout (floats): logits | values | actor_state | critic_state
#define LOGN  (TB_*A_)           // 9437184
#define VOFF_ LOGN
#define SOFF_ (LOGN + TB_)       // 9961472

#define S1_ (-1.4426950408889634f)   // -log2(e)   (r,z gates)
#define S2_ (-2.885390081777927f)    // -2*log2(e) (n gate)

__device__ __forceinline__ ushort f2bf(float f) {
  __hip_bfloat16 h = __float2bfloat16(f);
  return __builtin_bit_cast(ushort, h);
}
__device__ __forceinline__ uint cvt_pk_bf16(float lo, float hi) {
  uint r;
  asm("v_cvt_pk_bf16_f32 %0, %1, %2" : "=v"(r) : "v"(lo), "v"(hi));
  return r;
}
__device__ __forceinline__ f32x4 mfma16(short8 a, short8 b, f32x4 c) {
  return __builtin_amdgcn_mfma_f32_16x16x32_bf16(a, b, c, 0, 0, 0);
}

__global__ __launch_bounds__(256) void prep_kernel(
    const float* aW1, const float* aW2, const float* aWih, const float* aWhh, const float* aWl,
    const float* cW1, const float* cW2, const float* cWih, const float* cWhh, const float* cWv,
    ushort* wts) {
  int idx = blockIdx.x * 256 + threadIdx.x;
  if (idx >= 2*WBR) return;
  int br = idx / WBR, off = idx % WBR;
  float v;
  if      (off < W2OFF)  v = (br ? cW1  : aW1 )[off];
  else if (off < WIHOFF) v = (br ? cW2  : aW2 )[off - W2OFF];
  else if (off < WHHOFF) {
    int rel = off - WIHOFF;
    v = (br ? cWih : aWih)[rel];
    v *= (rel < 128*H_) ? S1_ : S2_;      // fold gate logistic scales
  }
  else if (off < WHDOFF) {
    int rel = off - WHHOFF;
    v = (br ? cWhh : aWhh)[rel];
    v *= (rel < 128*H_) ? S1_ : S2_;
  }
  else {
    int t = off - WHDOFF;
    if (br == 0) v = (t < A_*H_) ? aWl[t] : 0.f;
    else         v = (t < H_)    ? cWv[t] : 0.f;
  }
  wts[WBASE + idx] = f2bf(v);
}

// ---------------- phase 1: fused MLP, barrier-free, x -> ws (bf16, PLAIN row-major) ---
__global__ __launch_bounds__(256) void mlp_kernel(
    const float* __restrict__ obs, const ushort* __restrict__ wts,
    const float* __restrict__ ab1, const float* __restrict__ ab2,
    const float* __restrict__ cb1, const float* __restrict__ cb2,
    ushort* __restrict__ xout) {
  __shared__ __align__(16) ushort obsb[4][16 * D_];   // per-wave 4KB staged obs (bf16)
  __shared__ __align__(16) ushort htmp[4][16 * H_];   // per-wave 2KB, wave-local only
  const int tid = threadIdx.x;
  const int l = tid & 63, w = tid >> 6;
  const int lr = l & 15, lg = l >> 4;
  const int key = lr & 7;
  const long r0 = (long)blockIdx.x * 64;
  const f32x4 fzero = {0.f, 0.f, 0.f, 0.f};

  // stage this wave's 16 obs rows: fully-coalesced f32 loads -> cvt -> swizzled LDS
  {
    const float* src = obs + (r0 + (long)w * 16) * D_;
    #pragma unroll
    for (int i = 0; i < 8; ++i) {
      int ri = i * 2 + (l >> 5);          // row 0..15
      int cq = (l & 31) * 4;              // f32 col
      float4 v = *(const float4*)(src + ri * D_ + cq);
      uint lo = cvt_pk_bf16(v.x, v.y);
      uint hi = cvt_pk_bf16(v.z, v.w);
      int ch = (l & 31) >> 1;             // 16B chunk 0..15
      int chs = (ch & 8) | ((ch & 7) ^ (ri & 7));
      *(uint2*)(&obsb[w][ri * D_ + chs * 8 + (l & 1) * 4]) = uint2{lo, hi};
    }
  }
  // A-fragments from staged LDS (wave-local; compiler inserts lgkm waits)
  short8 af[4];
  #pragma unroll
  for (int ks = 0; ks < 4; ++ks) {
    int ch = ks * 4 + lg;
    int chs = (ch & 8) | ((ch & 7) ^ (lr & 7));
    af[ks] = *(const short8*)(&obsb[w][lr * D_ + chs * 8]);
  }

  #pragma unroll 1
  for (int br = 0; br < 2; ++br) {
    const ushort* wb = wts + WBASE + br * WBR;
    const float* b1 = br ? cb1 : ab1;
    const float* b2 = br ? cb2 : ab2;

    // ---- layer 1: [16,128] @ [128,64]
    f32x4 acc[4];
    #pragma unroll
    for (int nt = 0; nt < 4; ++nt) acc[nt] = fzero;
    #pragma unroll
    for (int ks = 0; ks < 4; ++ks) {
      #pragma unroll
      for (int nt = 0; nt < 4; ++nt) {
        int n = nt * 16 + lr;
        short8 b = *(const short8*)(wb + W1OFF + n * D_ + ks * 32 + lg * 8);
        acc[nt] = mfma16(af[ks], b, acc[nt]);
      }
    }
    // bias+relu -> htmp[w] (16B-unit swizzle, key=row&7), wave-local
    #pragma unroll
    for (int nt = 0; nt < 4; ++nt) {
      int coln = nt * 16 + lr;
      float bias = b1[coln];
      #pragma unroll
      for (int j = 0; j < 4; ++j) {
        int rw = lg * 4 + j;
        float v = fmaxf(acc[nt][j] + bias, 0.f);
        int idx = rw * H_ + ((((coln >> 3) ^ (rw & 7))) << 3) + (coln & 7);
        htmp[w][idx] = f2bf(v);
      }
    }
    // ---- layer 2: [16,64] @ [64,64]  (wave-local ds round-trip, no barrier)
    short8 a2[2];
    #pragma unroll
    for (int ks = 0; ks < 2; ++ks) {
      int c = ks * 4 + lg;
      a2[ks] = *(const short8*)(&htmp[w][lr * H_ + ((c ^ key) << 3)]);
    }
    f32x4 acc2[4];
    #pragma unroll
    for (int nt = 0; nt < 4; ++nt) acc2[nt] = fzero;
    #pragma unroll
    for (int ks = 0; ks < 2; ++ks) {
      #pragma unroll
      for (int nt = 0; nt < 4; ++nt) {
        int n = nt * 16 + lr;
        short8 b = *(const short8*)(wb + W2OFF + n * H_ + ks * 32 + lg * 8);
        acc2[nt] = mfma16(a2[ks], b, acc2[nt]);
      }
    }
    #pragma unroll
    for (int nt = 0; nt < 4; ++nt) {
      int coln = nt * 16 + lr;
      float bias = b2[coln];
      #pragma unroll
      for (int j = 0; j < 4; ++j) {
        int rw = lg * 4 + j;
        float v = fmaxf(acc2[nt][j] + bias, 0.f);
        int idx = rw * H_ + ((((coln >> 3) ^ (rw & 7))) << 3) + (coln & 7);
        htmp[w][idx] = f2bf(v);
      }
    }
    // de-swizzling copy: htmp[w] -> global x, PLAIN row-major
    {
      ushort* dp = xout + (size_t)br * XELEMS + (size_t)(r0 + w * 16) * H_;
      #pragma unroll
      for (int i = 0; i < 2; ++i) {
        int id = l + i * 64;          // 128 chunks of 16B
        int rr = id >> 3, cc = id & 7;
        uint4 v = *(const uint4*)(&htmp[w][rr * H_ + ((cc ^ (rr & 7)) << 3)]);
        *(uint4*)(dp + rr * H_ + (cc << 3)) = v;
      }
    }
  }
}

// ---------------- phase 2: GRU scan, dual wave-groups (actor: waves 0-3, critic: 4-7) -
__global__ __launch_bounds__(512, 1) void scan_kernel(
    const ushort* __restrict__ wts,     // ws + WBASE region
    const ushort* __restrict__ xin,     // ws x region (load-only view)
    ushort* __restrict__ hist,          // ws x region (store-only view; t-disjoint)
    const float* __restrict__ dones,
    const float* __restrict__ astate, const float* __restrict__ cstate,
    const float* __restrict__ abih, const float* __restrict__ abhh,
    const float* __restrict__ cbih, const float* __restrict__ cbhh,
    float* __restrict__ out) {
  __shared__ __align__(16) ushort hbuf[2][2][16 * H_];  // [grp][dbuf] h^T swizzled
  __shared__ __align__(8)  ushort dl16[T_ * 16];        // done flags, 16KB, shared
  const int tid = threadIdx.x;
  const int l = tid & 63, w = tid >> 6;       // w 0..7
  const int grp = w >> 2;                     // 0=actor, 1=critic
  const int w2 = w & 3;
  const int lr = l & 15, lg = l >> 4;
  const int b0 = blockIdx.x * 16;
  const f32x4 fzero = {0.f, 0.f, 0.f, 0.f};

  const ushort* wb = wts + grp * WBR;
  const ushort* xp = xin + (size_t)grp * XELEMS;
  ushort* hp = hist + (size_t)grp * XELEMS;
  const float* bihp = grp ? cbih : abih;
  const float* bhhp = grp ? cbhh : abhh;
  const float* st   = grp ? cstate : astate;

  // dones -> LDS flags (one-time, all 512 threads)
  #pragma unroll
  for (int i = 0; i < 4; ++i) {
    int s = tid + i * 512;              // 2048 float4 slots
    int t = s >> 2, p = s & 3;
    float4 v = *(const float4*)(dones + (size_t)t * B_ + b0 + p * 4);
    uint lo = (v.x != 0.f ? 1u : 0u) | ((v.y != 0.f ? 1u : 0u) << 16);
    uint hi = (v.z != 0.f ? 1u : 0u) | ((v.w != 0.f ? 1u : 0u) << 16);
    *(uint2*)(&dl16[t * 16 + p * 4]) = uint2{lo, hi};
  }

  // persistent weight A-fragments for THIS wave's branch (row = gate-col, k = h-col)
  short8 ihW[3][2], hhW[3][2];
  #pragma unroll
  for (int g = 0; g < 3; ++g) {
    int n = g * 64 + w2 * 16 + lr;
    #pragma unroll
    for (int ks = 0; ks < 2; ++ks) {
      ihW[g][ks] = *(const short8*)(wb + WIHOFF + n * H_ + ks * 32 + lg * 8);
      hhW[g][ks] = *(const short8*)(wb + WHHOFF + n * H_ + ks * 32 + lg * 8);
    }
  }

  // biases for this lane's 4 gate-cols (scaled to match prescaled weights)
  const int o4 = w2 * 16 + lg * 4;
  f32x4 bs0, bs1, binv, bhnv;
  {
    float4 a0 = *(const float4*)(bihp + o4),       h0v = *(const float4*)(bhhp + o4);
    float4 a1 = *(const float4*)(bihp + 64 + o4),  h1v = *(const float4*)(bhhp + 64 + o4);
    float4 a2 = *(const float4*)(bihp + 128 + o4), h2v = *(const float4*)(bhhp + 128 + o4);
    bs0[0]=S1_*(a0.x+h0v.x); bs0[1]=S1_*(a0.y+h0v.y); bs0[2]=S1_*(a0.z+h0v.z); bs0[3]=S1_*(a0.w+h0v.w);
    bs1[0]=S1_*(a1.x+h1v.x); bs1[1]=S1_*(a1.y+h1v.y); bs1[2]=S1_*(a1.z+h1v.z); bs1[3]=S1_*(a1.w+h1v.w);
    binv[0]=S2_*a2.x; binv[1]=S2_*a2.y; binv[2]=S2_*a2.z; binv[3]=S2_*a2.w;
    bhnv[0]=S2_*h2v.x; bhnv[1]=S2_*h2v.y; bhnv[2]=S2_*h2v.z; bhnv[3]=S2_*h2v.w;
  }

  // hbuf addressing (ushort units). write: 8B half-unit; read: 16B unit, XOR key lr&7
  const int myW = lr * H_ + (((w2 * 2 + (lg >> 1)) ^ (lr & 7)) << 3) + (lg & 1) * 4;
  const int rdA = lr * H_ + (((0 + lg) ^ (lr & 7)) << 3);
  const int rdB = lr * H_ + (((4 + lg) ^ (lr & 7)) << 3);

  // h init: lane holds (batch b0+lr, cols o4..o4+3), fp32
  float h_old[4];
  {
    float4 h0v = *(const float4*)(st + (size_t)(b0 + lr) * H_ + o4);
    bool rs0 = (dones[b0 + lr] != 0.f);
    h_old[0] = rs0 ? 0.f : h0v.x; h_old[1] = rs0 ? 0.f : h0v.y;
    h_old[2] = rs0 ? 0.f : h0v.z; h_old[3] = rs0 ? 0.f : h0v.w;
    uint2 hv;
    hv.x = cvt_pk_bf16(h_old[0], h_old[1]);
    hv.y = cvt_pk_bf16(h_old[2], h_old[3]);
    *(uint2*)(&hbuf[grp][0][myW]) = hv;
  }

  __syncthreads();   // dl16 + hbuf[.][0] visible

  auto loadx = [&](int t, short8 (&f)[2]) {
    const ushort* p = xp + ((size_t)t * B_ + b0 + lr) * H_;
    f[0] = *(const short8*)(p + lg * 8);
    f[1] = *(const short8*)(p + 32 + lg * 8);
  };

  short8 buf0[2], buf1[2];
  loadx(0, buf0); loadx(1, buf1);

  int cur = 0;

  auto dostep = [&](int t, short8 (&xb)[2]) {
    // h_{t-1}^T fragments (B-operand) from this group's LDS buffer
    short8 hf0 = *(const short8*)(&hbuf[grp][cur][rdA]);
    short8 hf1 = *(const short8*)(&hbuf[grp][cur][rdB]);
    int tn = t + 1;
    ushort dn = dl16[((tn < T_) ? tn : 0) * 16 + lr];
    bool rs = (tn < T_) && (dn != 0);

    f32x4 gi0 = fzero, gi1 = fzero, gi2 = fzero;
    gi0 = mfma16(ihW[0][0], xb[0], gi0); gi0 = mfma16(ihW[0][1], xb[1], gi0);
    gi1 = mfma16(ihW[1][0], xb[0], gi1); gi1 = mfma16(ihW[1][1], xb[1], gi1);
    gi2 = mfma16(ihW[2][0], xb[0], gi2); gi2 = mfma16(ihW[2][1], xb[1], gi2);
    f32x4 gh0 = fzero, gh1 = fzero, gh2 = fzero;
    gh0 = mfma16(hhW[0][0], hf0, gh0); gh0 = mfma16(hhW[0][1], hf1, gh0);
    gh1 = mfma16(hhW[1][0], hf0, gh1); gh1 = mfma16(hhW[1][1], hf1, gh1);
    gh2 = mfma16(hhW[2][0], hf0, gh2); gh2 = mfma16(hhW[2][1], hf1, gh2);

    // prefetch t+2 into the consumed buffer
    int tp = (t + 2 < T_) ? t + 2 : T_ - 1;
    loadx(tp, xb);

    // gates (weights prescaled: sigm = rcp(1+exp2(s)); tanh = 2*rcp(1+exp2(s))-1)
    float hn[4];
    #pragma unroll
    for (int j = 0; j < 4; ++j) {
      float sr = gi0[j] + gh0[j] + bs0[j];
      float rr = __builtin_amdgcn_rcpf(1.f + __builtin_amdgcn_exp2f(sr));
      float sz = gi1[j] + gh1[j] + bs1[j];
      float zz = __builtin_amdgcn_rcpf(1.f + __builtin_amdgcn_exp2f(sz));
      float tg = gh2[j] + bhnv[j];
      float sn = fmaf(rr, tg, gi2[j] + binv[j]);
      float qq = __builtin_amdgcn_rcpf(1.f + __builtin_amdgcn_exp2f(sn));
      float nn = fmaf(2.f, qq, -1.f);
      hn[j] = fmaf(zz, h_old[j] - nn, nn);
    }
    // h history (pre-reset), packed row-major dwordx2 — fully coalesced
    uint2 hv;
    hv.x = cvt_pk_bf16(hn[0], hn[1]);
    hv.y = cvt_pk_bf16(hn[2], hn[3]);
    *(uint2*)(hp + ((size_t)t * B_ + b0 + lr) * H_ + o4) = hv;
    // reset with done_{t+1}; write h_t to other buffer
    uint2 hz;
    hz.x = rs ? 0u : hv.x;
    hz.y = rs ? 0u : hv.y;
    h_old[0] = rs ? 0.f : hn[0]; h_old[1] = rs ? 0.f : hn[1];
    h_old[2] = rs ? 0.f : hn[2]; h_old[3] = rs ? 0.f : hn[3];
    int nxt = cur ^ 1;
    *(uint2*)(&hbuf[grp][nxt][myW]) = hz;
    asm volatile("s_waitcnt lgkmcnt(0)" ::: "memory");
    __builtin_amdgcn_s_barrier();
    cur = nxt;
  };

  for (int it = 0; it < T_ / 2; ++it) {
    dostep(2 * it,     buf0);
    dostep(2 * it + 1, buf1);
  }

  // final states (fp32, post step 511; no reset applied on last step)
  float4 fs = {h_old[0], h_old[1], h_old[2], h_old[3]};
  *(float4*)(out + SOFF_ + (size_t)grp * (B_ * H_) + (size_t)(b0 + lr) * H_ + o4) = fs;
}

// ---------------- phase 3: heads (logits + values), LDS-staged coalesced stores -------
__global__ __launch_bounds__(256) void head_kernel(
    const ushort* __restrict__ ws,
    const float* __restrict__ abl, const float* __restrict__ cbv,
    float* __restrict__ out) {
  __shared__ float ltile[4][16 * A_];               // per-wave 1.125KB, wave-local
  const int tid = threadIdx.x;
  const int l = tid & 63, w = tid >> 6;
  const int lr = l & 15, lg = l >> 4;
  const long r0 = (long)blockIdx.x * 64 + w * 16;   // TB-row base for this wave
  const f32x4 fzero = {0.f, 0.f, 0.f, 0.f};

  const ushort* hA = ws + r0 * H_;
  const ushort* hC = ws + XELEMS + r0 * H_;
  short8 aA[2], aC[2];
  #pragma unroll
  for (int ks = 0; ks < 2; ++ks) {
    aA[ks] = *(const short8*)(hA + lr * H_ + ks * 32 + lg * 8);
    aC[ks] = *(const short8*)(hC + lr * H_ + ks * 32 + lg * 8);
  }
  // logits: [16,64]@[64,32] (Wl zero-padded to 32 rows)
  const ushort* wbA = ws + WBASE + WHDOFF;
  const ushort* wbC = ws + WBASE + WBR + WHDOFF;
  f32x4 acc[2];
  acc[0] = fzero; acc[1] = fzero;
  #pragma unroll
  for (int nt = 0; nt < 2; ++nt) {
    int n = nt * 16 + lr;
    #pragma unroll
    for (int ks = 0; ks < 2; ++ks) {
      short8 b = *(const short8*)(wbA + n * H_ + ks * 32 + lg * 8);
      acc[nt] = mfma16(aA[ks], b, acc[nt]);
    }
  }
  // values: [16,64]@[64,16] (only n==0 nonzero)
  f32x4 vacc = fzero;
  {
    int n = lr;
    #pragma unroll
    for (int ks = 0; ks < 2; ++ks) {
      short8 b = *(const short8*)(wbC + n * H_ + ks * 32 + lg * 8);
      vacc = mfma16(aC[ks], b, vacc);
    }
  }
  // stage logits tile into LDS (wave-local), then coalesced global stores
  #pragma unroll
  for (int nt = 0; nt < 2; ++nt) {
    int n = nt * 16 + lr;
    if (n < A_) {
      float bias = abl[n];
      #pragma unroll
      for (int j = 0; j < 4; ++j)
        ltile[w][(lg * 4 + j) * A_ + n] = acc[nt][j] + bias;
    }
  }
  asm volatile("s_waitcnt lgkmcnt(0)" ::: "memory");
  #pragma unroll
  for (int i = 0; i < 5; ++i) {
    int idx = l + i * 64;             // 288 floats = 16 rows x 18
    if (idx < 16 * A_)
      out[r0 * A_ + idx] = ltile[w][idx];
  }
  if (lr == 0) {
    float bias = cbv[0];
    #pragma unroll
    for (int j = 0; j < 4; ++j)
      out[VOFF_ + r0 + lg * 4 + j] = vacc[j] + bias;
  }
}

extern "C" void kernel_launch(void* const* d_in, const int* in_sizes, int n_in,
                              void* d_out, int out_size, void* d_ws, size_t ws_size,
                              hipStream_t stream) {
  const float* obs    = (const float*)d_in[0];
  const float* dones  = (const float*)d_in[1];
  const float* astate = (const float*)d_in[2];
  const float* cstate = (const float*)d_in[3];
  const float* aW1  = (const float*)d_in[4];
  const float* ab1  = (const float*)d_in[5];
  const float* aW2  = (const float*)d_in[6];
  const float* ab2  = (const float*)d_in[7];
  const float* aWih = (const float*)d_in[8];
  const float* aWhh = (const float*)d_in[9];
  const float* abih = (const float*)d_in[10];
  const float* abhh = (const float*)d_in[11];
  const float* aWl  = (const float*)d_in[12];
  const float* abl  = (const float*)d_in[13];
  const float* cW1  = (const float*)d_in[14];
  const float* cb1  = (const float*)d_in[15];
  const float* cW2  = (const float*)d_in[16];
  const float* cb2  = (const float*)d_in[17];
  const float* cWih = (const float*)d_in[18];
  const float* cWhh = (const float*)d_in[19];
  const float* cbih = (const float*)d_in[20];
  const float* cbhh = (const float*)d_in[21];
  const float* cWv  = (const float*)d_in[22];
  const float* cbv  = (const float*)d_in[23];
  ushort* ws = (ushort*)d_ws;
  float* out = (float*)d_out;

  const size_t need = ((size_t)2 * XELEMS + 2 * WBR) * 2;
  if (ws_size < need) {
    hipMemsetAsync(d_out, 0x7F, 16, stream);
    return;
  }

  hipLaunchKernelGGL(prep_kernel, dim3(304), dim3(256), 0, stream,
                     aW1, aW2, aWih, aWhh, aWl, cW1, cW2, cWih, cWhh, cWv, ws);
  hipLaunchKernelGGL(mlp_kernel, dim3(TB_ / 64), dim3(256), 0, stream,
                     obs, ws, ab1, ab2, cb1, cb2, ws);
  hipLaunchKernelGGL(scan_kernel, dim3(64), dim3(512), 0, stream,
                     ws + WBASE, ws, ws, dones, astate, cstate,
                     abih, abhh, cbih, cbhh, out);
  hipLaunchKernelGGL(head_kernel, dim3(TB_ / 64), dim3(256), 0, stream,
                     ws, abl, cbv, out);
}

// Round 7
// 606.975 us; speedup vs baseline: 1.0476x; 1.0063x over previous
//
#include <hip/hip_runtime.h>
#include <hip/hip_bf16.h>

typedef short short8 __attribute__((ext_vector_type(8)));
typedef float f32x4 __attribute__((ext_vector_type(4)));

#define T_ 512
#define B_ 1024
#define D_ 128
#define H_ 64
#define A_ 18
#define TB_ (T_*B_)

// ws layout (ushort units): [x_actor | x_critic | bf16 weights]
#define XELEMS (TB_*H_)          // 33554432 per branch
#define WBASE  (2*XELEMS)
#define WBR    38912             // per-branch weight elems
#define W1OFF  0
#define W2OFF  8192
#define WIHOFF 12288
#define WHHOFF 24576
#define WHDOFF 36864

// out layout (floats): logits | values | actor_state | critic_state
#define LOGN  (TB_*A_)           // 9437184
#define VOFF_ LOGN
#define SOFF_ (LOGN + TB_)       // 9961472
#define POFF_ 3000000            // probe scratch inside logits region (overwritten by head)

#define S1_ (-1.4426950408889634f)   // -log2(e)   (r,z gates)
#define S2_ (-2.885390081777927f)    // -2*log2(e) (n gate)

__device__ __forceinline__ ushort f2bf(float f) {
  __hip_bfloat16 h = __float2bfloat16(f);
  return __builtin_bit_cast(ushort, h);
}
__device__ __forceinline__ uint cvt_pk_bf16(float lo, float hi) {
  uint r;
  asm("v_cvt_pk_bf16_f32 %0, %1, %2" : "=v"(r) : "v"(lo), "v"(hi));
  return r;
}
__device__ __forceinline__ f32x4 mfma16(short8 a, short8 b, f32x4 c) {
  return __builtin_amdgcn_mfma_f32_16x16x32_bf16(a, b, c, 0, 0, 0);
}

__global__ __launch_bounds__(256) void prep_kernel(
    const float* aW1, const float* aW2, const float* aWih, const float* aWhh, const float* aWl,
    const float* cW1, const float* cW2, const float* cWih, const float* cWhh, const float* cWv,
    ushort* wts) {
  int idx = blockIdx.x * 256 + threadIdx.x;
  if (idx >= 2*WBR) return;
  int br = idx / WBR, off = idx % WBR;
  float v;
  if      (off < W2OFF)  v = (br ? cW1  : aW1 )[off];
  else if (off < WIHOFF) v = (br ? cW2  : aW2 )[off - W2OFF];
  else if (off < WHHOFF) {
    int rel = off - WIHOFF;
    v = (br ? cWih : aWih)[rel];
    v *= (rel < 128*H_) ? S1_ : S2_;      // fold gate logistic scales
  }
  else if (off < WHDOFF) {
    int rel = off - WHHOFF;
    v = (br ? cWhh : aWhh)[rel];
    v *= (rel < 128*H_) ? S1_ : S2_;
  }
  else {
    int t = off - WHDOFF;
    if (br == 0) v = (t < A_*H_) ? aWl[t] : 0.f;
    else         v = (t < H_)    ? cWv[t] : 0.f;
  }
  wts[WBASE + idx] = f2bf(v);
}

// ---------------- phase 1: fused MLP, barrier-free, x -> ws (bf16, PLAIN row-major) ---
__global__ __launch_bounds__(256) void mlp_kernel(
    const float* __restrict__ obs, const ushort* __restrict__ wts,
    const float* __restrict__ ab1, const float* __restrict__ ab2,
    const float* __restrict__ cb1, const float* __restrict__ cb2,
    ushort* __restrict__ xout) {
  __shared__ __align__(16) ushort obsb[4][16 * D_];   // per-wave 4KB staged obs (bf16)
  __shared__ __align__(16) ushort htmp[4][16 * H_];   // per-wave 2KB, wave-local only
  const int tid = threadIdx.x;
  const int l = tid & 63, w = tid >> 6;
  const int lr = l & 15, lg = l >> 4;
  const int key = lr & 7;
  const long r0 = (long)blockIdx.x * 64;
  const f32x4 fzero = {0.f, 0.f, 0.f, 0.f};

  // stage this wave's 16 obs rows: fully-coalesced f32 loads -> cvt -> swizzled LDS
  {
    const float* src = obs + (r0 + (long)w * 16) * D_;
    #pragma unroll
    for (int i = 0; i < 8; ++i) {
      int ri = i * 2 + (l >> 5);          // row 0..15
      int cq = (l & 31) * 4;              // f32 col
      float4 v = *(const float4*)(src + ri * D_ + cq);
      uint lo = cvt_pk_bf16(v.x, v.y);
      uint hi = cvt_pk_bf16(v.z, v.w);
      int ch = (l & 31) >> 1;             // 16B chunk 0..15
      int chs = (ch & 8) | ((ch & 7) ^ (ri & 7));
      *(uint2*)(&obsb[w][ri * D_ + chs * 8 + (l & 1) * 4]) = uint2{lo, hi};
    }
  }
  short8 af[4];
  #pragma unroll
  for (int ks = 0; ks < 4; ++ks) {
    int ch = ks * 4 + lg;
    int chs = (ch & 8) | ((ch & 7) ^ (lr & 7));
    af[ks] = *(const short8*)(&obsb[w][lr * D_ + chs * 8]);
  }

  #pragma unroll 1
  for (int br = 0; br < 2; ++br) {
    const ushort* wb = wts + WBASE + br * WBR;
    const float* b1 = br ? cb1 : ab1;
    const float* b2 = br ? cb2 : ab2;

    f32x4 acc[4];
    #pragma unroll
    for (int nt = 0; nt < 4; ++nt) acc[nt] = fzero;
    #pragma unroll
    for (int ks = 0; ks < 4; ++ks) {
      #pragma unroll
      for (int nt = 0; nt < 4; ++nt) {
        int n = nt * 16 + lr;
        short8 b = *(const short8*)(wb + W1OFF + n * D_ + ks * 32 + lg * 8);
        acc[nt] = mfma16(af[ks], b, acc[nt]);
      }
    }
    #pragma unroll
    for (int nt = 0; nt < 4; ++nt) {
      int coln = nt * 16 + lr;
      float bias = b1[coln];
      #pragma unroll
      for (int j = 0; j < 4; ++j) {
        int rw = lg * 4 + j;
        float v = fmaxf(acc[nt][j] + bias, 0.f);
        int idx = rw * H_ + ((((coln >> 3) ^ (rw & 7))) << 3) + (coln & 7);
        htmp[w][idx] = f2bf(v);
      }
    }
    short8 a2[2];
    #pragma unroll
    for (int ks = 0; ks < 2; ++ks) {
      int c = ks * 4 + lg;
      a2[ks] = *(const short8*)(&htmp[w][lr * H_ + ((c ^ key) << 3)]);
    }
    f32x4 acc2[4];
    #pragma unroll
    for (int nt = 0; nt < 4; ++nt) acc2[nt] = fzero;
    #pragma unroll
    for (int ks = 0; ks < 2; ++ks) {
      #pragma unroll
      for (int nt = 0; nt < 4; ++nt) {
        int n = nt * 16 + lr;
        short8 b = *(const short8*)(wb + W2OFF + n * H_ + ks * 32 + lg * 8);
        acc2[nt] = mfma16(a2[ks], b, acc2[nt]);
      }
    }
    #pragma unroll
    for (int nt = 0; nt < 4; ++nt) {
      int coln = nt * 16 + lr;
      float bias = b2[coln];
      #pragma unroll
      for (int j = 0; j < 4; ++j) {
        int rw = lg * 4 + j;
        float v = fmaxf(acc2[nt][j] + bias, 0.f);
        int idx = rw * H_ + ((((coln >> 3) ^ (rw & 7))) << 3) + (coln & 7);
        htmp[w][idx] = f2bf(v);
      }
    }
    {
      ushort* dp = xout + (size_t)br * XELEMS + (size_t)(r0 + w * 16) * H_;
      #pragma unroll
      for (int i = 0; i < 2; ++i) {
        int id = l + i * 64;          // 128 chunks of 16B
        int rr = id >> 3, cc = id & 7;
        uint4 v = *(const uint4*)(&htmp[w][rr * H_ + ((cc ^ (rr & 7)) << 3)]);
        *(uint4*)(dp + rr * H_ + (cc << 3)) = v;
      }
    }
  }
}

// ---------------- phase 2: GRU scan body (R4 structure), templated for ablation -------
// VAR 0: real/control. VAR 1: transcendentals->muls. VAR 2: no barrier, reg h-feedback.
// VAR 3: no per-step x loads (keepalive).  STEPS: 512 real / 64 probes.
template<int VAR, int STEPS>
__device__ __forceinline__ void scan_body(
    const ushort* __restrict__ wts, const ushort* __restrict__ xin,
    ushort* __restrict__ hist, size_t hstride,
    const float* __restrict__ dones,
    const float* __restrict__ astate, const float* __restrict__ cstate,
    const float* __restrict__ abih, const float* __restrict__ abhh,
    const float* __restrict__ cbih, const float* __restrict__ cbhh,
    float* __restrict__ stout) {
  __shared__ __align__(16) ushort hbuf[2][16 * H_];
  __shared__ __align__(8)  ushort dl16[STEPS * 16];
  const int tid = threadIdx.x;
  const int l = tid & 63, w = tid >> 6;
  const int lr = l & 15, lg = l >> 4;
  const int grp = blockIdx.x & 1;
  const int b0 = (blockIdx.x >> 1) * 16;
  const f32x4 fzero = {0.f, 0.f, 0.f, 0.f};
  constexpr bool FAKE = (VAR == 1);

  const ushort* wb = wts + grp * WBR;
  const ushort* xp = xin + (size_t)grp * XELEMS;
  ushort* hp = hist + (size_t)grp * hstride;
  const float* bihp = grp ? cbih : abih;
  const float* bhhp = grp ? cbhh : abhh;
  const float* st   = grp ? cstate : astate;

  // dones -> LDS flags
  constexpr int NI = STEPS / 64;
  #pragma unroll
  for (int i = 0; i < NI; ++i) {
    int s = tid + i * 256;
    int t = s >> 2, p = s & 3;
    float4 v = *(const float4*)(dones + (size_t)t * B_ + b0 + p * 4);
    uint lo = (v.x != 0.f ? 1u : 0u) | ((v.y != 0.f ? 1u : 0u) << 16);
    uint hi = (v.z != 0.f ? 1u : 0u) | ((v.w != 0.f ? 1u : 0u) << 16);
    *(uint2*)(&dl16[t * 16 + p * 4]) = uint2{lo, hi};
  }

  short8 ihW[3][2], hhW[3][2];
  #pragma unroll
  for (int g = 0; g < 3; ++g) {
    int n = g * 64 + w * 16 + lr;
    #pragma unroll
    for (int ks = 0; ks < 2; ++ks) {
      ihW[g][ks] = *(const short8*)(wb + WIHOFF + n * H_ + ks * 32 + lg * 8);
      hhW[g][ks] = *(const short8*)(wb + WHHOFF + n * H_ + ks * 32 + lg * 8);
    }
  }

  const int o4 = w * 16 + lg * 4;
  f32x4 bs0, bs1, binv, bhnv;
  {
    float4 a0 = *(const float4*)(bihp + o4),       h0v = *(const float4*)(bhhp + o4);
    float4 a1 = *(const float4*)(bihp + 64 + o4),  h1v = *(const float4*)(bhhp + 64 + o4);
    float4 a2 = *(const float4*)(bihp + 128 + o4), h2v = *(const float4*)(bhhp + 128 + o4);
    bs0[0]=S1_*(a0.x+h0v.x); bs0[1]=S1_*(a0.y+h0v.y); bs0[2]=S1_*(a0.z+h0v.z); bs0[3]=S1_*(a0.w+h0v.w);
    bs1[0]=S1_*(a1.x+h1v.x); bs1[1]=S1_*(a1.y+h1v.y); bs1[2]=S1_*(a1.z+h1v.z); bs1[3]=S1_*(a1.w+h1v.w);
    binv[0]=S2_*a2.x; binv[1]=S2_*a2.y; binv[2]=S2_*a2.z; binv[3]=S2_*a2.w;
    bhnv[0]=S2_*h2v.x; bhnv[1]=S2_*h2v.y; bhnv[2]=S2_*h2v.z; bhnv[3]=S2_*h2v.w;
  }

  const int myW = lr * H_ + (((w * 2 + (lg >> 1)) ^ (lr & 7)) << 3) + (lg & 1) * 4;
  const int rdA = lr * H_ + (((0 + lg) ^ (lr & 7)) << 3);
  const int rdB = lr * H_ + (((4 + lg) ^ (lr & 7)) << 3);

  float h_old[4];
  uint2 hzr;
  {
    float4 h0v = *(const float4*)(st + (size_t)(b0 + lr) * H_ + o4);
    bool rs0 = (dones[b0 + lr] != 0.f);
    h_old[0] = rs0 ? 0.f : h0v.x; h_old[1] = rs0 ? 0.f : h0v.y;
    h_old[2] = rs0 ? 0.f : h0v.z; h_old[3] = rs0 ? 0.f : h0v.w;
    uint2 hv;
    hv.x = cvt_pk_bf16(h_old[0], h_old[1]);
    hv.y = cvt_pk_bf16(h_old[2], h_old[3]);
    hzr = hv;
    *(uint2*)(&hbuf[0][myW]) = hv;
  }

  __syncthreads();

  auto loadx = [&](int t, short8 (&f)[2]) {
    const ushort* p = xp + ((size_t)t * B_ + b0 + lr) * H_;
    f[0] = *(const short8*)(p + lg * 8);
    f[1] = *(const short8*)(p + 32 + lg * 8);
  };

  short8 buf0[2], buf1[2], buf2[2], buf3[2];
  loadx(0, buf0); loadx(1, buf1); loadx(2, buf2); loadx(3, buf3);

  int cur = 0;

  auto dostep = [&](int t, short8 (&xb)[2]) {
    short8 hf0, hf1;
    if constexpr (VAR != 2) {
      hf0 = *(const short8*)(&hbuf[cur][rdA]);
      hf1 = *(const short8*)(&hbuf[cur][rdB]);
    } else {
      uint4 c = {hzr.x, hzr.y, hzr.x, hzr.y};
      hf0 = __builtin_bit_cast(short8, c);
      hf1 = hf0;
    }
    int tn = t + 1;
    ushort dn = dl16[((tn < STEPS) ? tn : 0) * 16 + lr];
    bool rs = (tn < STEPS) && (dn != 0);

    f32x4 gi0 = fzero, gi1 = fzero, gi2 = fzero;
    gi0 = mfma16(ihW[0][0], xb[0], gi0); gi0 = mfma16(ihW[0][1], xb[1], gi0);
    gi1 = mfma16(ihW[1][0], xb[0], gi1); gi1 = mfma16(ihW[1][1], xb[1], gi1);
    gi2 = mfma16(ihW[2][0], xb[0], gi2); gi2 = mfma16(ihW[2][1], xb[1], gi2);
    f32x4 ga0 = fzero, ga1 = fzero, ga2 = fzero, gb0 = fzero, gb1 = fzero, gb2 = fzero;
    ga0 = mfma16(hhW[0][0], hf0, ga0); gb0 = mfma16(hhW[0][1], hf1, gb0);
    ga1 = mfma16(hhW[1][0], hf0, ga1); gb1 = mfma16(hhW[1][1], hf1, gb1);
    ga2 = mfma16(hhW[2][0], hf0, ga2); gb2 = mfma16(hhW[2][1], hf1, gb2);

    if constexpr (VAR != 3) {
      int tp = (t + 4 < STEPS) ? t + 4 : STEPS - 1;
      loadx(tp, xb);
    } else {
      asm volatile("" : "+v"(*(uint*)&xb[0]), "+v"(*(uint*)&xb[1]));
    }

    float hn[4];
    #pragma unroll
    for (int j = 0; j < 4; ++j) {
      float sr = gi0[j] + ga0[j] + gb0[j] + bs0[j];
      float er = FAKE ? sr * 0.570043f : __builtin_amdgcn_exp2f(sr);
      float rr = FAKE ? (1.f + er) * 0.993f : __builtin_amdgcn_rcpf(1.f + er);
      float sz = gi1[j] + ga1[j] + gb1[j] + bs1[j];
      float ez = FAKE ? sz * 0.570043f : __builtin_amdgcn_exp2f(sz);
      float zz = FAKE ? (1.f + ez) * 0.993f : __builtin_amdgcn_rcpf(1.f + ez);
      float tg = ga2[j] + gb2[j] + bhnv[j];
      float sn = fmaf(rr, tg, gi2[j] + binv[j]);
      float en = FAKE ? sn * 0.570043f : __builtin_amdgcn_exp2f(sn);
      float qq = FAKE ? (1.f + en) * 0.993f : __builtin_amdgcn_rcpf(1.f + en);
      float nn = fmaf(2.f, qq, -1.f);
      hn[j] = fmaf(zz, h_old[j] - nn, nn);
    }
    uint2 hv;
    hv.x = cvt_pk_bf16(hn[0], hn[1]);
    hv.y = cvt_pk_bf16(hn[2], hn[3]);
    *(uint2*)(hp + ((size_t)t * B_ + b0 + lr) * H_ + o4) = hv;   // history (pre-reset)
    uint2 hz;
    hz.x = rs ? 0u : hv.x;
    hz.y = rs ? 0u : hv.y;
    h_old[0] = rs ? 0.f : hn[0]; h_old[1] = rs ? 0.f : hn[1];
    h_old[2] = rs ? 0.f : hn[2]; h_old[3] = rs ? 0.f : hn[3];
    hzr = hz;
    int nxt = cur ^ 1;
    *(uint2*)(&hbuf[nxt][myW]) = hz;
    if constexpr (VAR != 2) {
      asm volatile("s_waitcnt lgkmcnt(0)" ::: "memory");
      __builtin_amdgcn_s_barrier();
    }
    cur = nxt;
  };

  for (int it = 0; it < STEPS / 4; ++it) {
    dostep(4 * it,     buf0);
    dostep(4 * it + 1, buf1);
    dostep(4 * it + 2, buf2);
    dostep(4 * it + 3, buf3);
  }

  float4 fs = {h_old[0], h_old[1], h_old[2], h_old[3]};
  *(float4*)(stout + (size_t)grp * (B_ * H_) + (size_t)(b0 + lr) * H_ + o4) = fs;
}

__global__ __launch_bounds__(256, 1) void scan_kernel(
    const ushort* __restrict__ wts, const ushort* __restrict__ xin,
    ushort* __restrict__ hist, const float* __restrict__ dones,
    const float* __restrict__ astate, const float* __restrict__ cstate,
    const float* __restrict__ abih, const float* __restrict__ abhh,
    const float* __restrict__ cbih, const float* __restrict__ cbhh,
    float* __restrict__ out) {
  scan_body<0, T_>(wts, xin, hist, (size_t)XELEMS, dones, astate, cstate,
                   abih, abhh, cbih, cbhh, out + SOFF_);
}

template<int VAR>
__global__ __launch_bounds__(256, 1) void probe_kernel(
    const ushort* __restrict__ wts, const ushort* __restrict__ xin,
    ushort* __restrict__ phist, const float* __restrict__ dones,
    const float* __restrict__ astate, const float* __restrict__ cstate,
    const float* __restrict__ abih, const float* __restrict__ abhh,
    const float* __restrict__ cbih, const float* __restrict__ cbhh,
    float* __restrict__ pstate) {
  scan_body<VAR, 64>(wts, xin, phist, (size_t)64 * B_ * H_, dones, astate, cstate,
                     abih, abhh, cbih, cbhh, pstate);
}

// ---------------- phase 3: heads (logits + values), LDS-staged coalesced stores -------
__global__ __launch_bounds__(256) void head_kernel(
    const ushort* __restrict__ ws,
    const float* __restrict__ abl, const float* __restrict__ cbv,
    float* __restrict__ out) {
  __shared__ float ltile[4][16 * A_];
  const int tid = threadIdx.x;
  const int l = tid & 63, w = tid >> 6;
  const int lr = l & 15, lg = l >> 4;
  const long r0 = (long)blockIdx.x * 64 + w * 16;
  const f32x4 fzero = {0.f, 0.f, 0.f, 0.f};

  const ushort* hA = ws + r0 * H_;
  const ushort* hC = ws + XELEMS + r0 * H_;
  short8 aA[2], aC[2];
  #pragma unroll
  for (int ks = 0; ks < 2; ++ks) {
    aA[ks] = *(const short8*)(hA + lr * H_ + ks * 32 + lg * 8);
    aC[ks] = *(const short8*)(hC + lr * H_ + ks * 32 + lg * 8);
  }
  const ushort* wbA = ws + WBASE + WHDOFF;
  const ushort* wbC = ws + WBASE + WBR + WHDOFF;
  f32x4 acc[2];
  acc[0] = fzero; acc[1] = fzero;
  #pragma unroll
  for (int nt = 0; nt < 2; ++nt) {
    int n = nt * 16 + lr;
    #pragma unroll
    for (int ks = 0; ks < 2; ++ks) {
      short8 b = *(const short8*)(wbA + n * H_ + ks * 32 + lg * 8);
      acc[nt] = mfma16(aA[ks], b, acc[nt]);
    }
  }
  f32x4 vacc = fzero;
  {
    int n = lr;
    #pragma unroll
    for (int ks = 0; ks < 2; ++ks) {
      short8 b = *(const short8*)(wbC + n * H_ + ks * 32 + lg * 8);
      vacc = mfma16(aC[ks], b, vacc);
    }
  }
  #pragma unroll
  for (int nt = 0; nt < 2; ++nt) {
    int n = nt * 16 + lr;
    if (n < A_) {
      float bias = abl[n];
      #pragma unroll
      for (int j = 0; j < 4; ++j)
        ltile[w][(lg * 4 + j) * A_ + n] = acc[nt][j] + bias;
    }
  }
  asm volatile("s_waitcnt lgkmcnt(0)" ::: "memory");
  #pragma unroll
  for (int i = 0; i < 5; ++i) {
    int idx = l + i * 64;
    if (idx < 16 * A_)
      out[r0 * A_ + idx] = ltile[w][idx];
  }
  if (lr == 0) {
    float bias = cbv[0];
    #pragma unroll
    for (int j = 0; j < 4; ++j)
      out[VOFF_ + r0 + lg * 4 + j] = vacc[j] + bias;
  }
}

extern "C" void kernel_launch(void* const* d_in, const int* in_sizes, int n_in,
                              void* d_out, int out_size, void* d_ws, size_t ws_size,
                              hipStream_t stream) {
  const float* obs    = (const float*)d_in[0];
  const float* dones  = (const float*)d_in[1];
  const float* astate = (const float*)d_in[2];
  const float* cstate = (const float*)d_in[3];
  const float* aW1  = (const float*)d_in[4];
  const float* ab1  = (const float*)d_in[5];
  const float* aW2  = (const float*)d_in[6];
  const float* ab2  = (const float*)d_in[7];
  const float* aWih = (const float*)d_in[8];
  const float* aWhh = (const float*)d_in[9];
  const float* abih = (const float*)d_in[10];
  const float* abhh = (const float*)d_in[11];
  const float* aWl  = (const float*)d_in[12];
  const float* abl  = (const float*)d_in[13];
  const float* cW1  = (const float*)d_in[14];
  const float* cb1  = (const float*)d_in[15];
  const float* cW2  = (const float*)d_in[16];
  const float* cb2  = (const float*)d_in[17];
  const float* cWih = (const float*)d_in[18];
  const float* cWhh = (const float*)d_in[19];
  const float* cbih = (const float*)d_in[20];
  const float* cbhh = (const float*)d_in[21];
  const float* cWv  = (const float*)d_in[22];
  const float* cbv  = (const float*)d_in[23];
  ushort* ws = (ushort*)d_ws;
  float* out = (float*)d_out;

  const size_t need = ((size_t)2 * XELEMS + 2 * WBR) * 2;
  if (ws_size < need) {
    hipMemsetAsync(d_out, 0x7F, 16, stream);
    return;
  }

  hipLaunchKernelGGL(prep_kernel, dim3(304), dim3(256), 0, stream,
                     aW1, aW2, aWih, aWhh, aWl, cW1, cW2, cWih, cWhh, cWv, ws);
  hipLaunchKernelGGL(mlp_kernel, dim3(TB_ / 64), dim3(256), 0, stream,
                     obs, ws, ab1, ab2, cb1, cb2, ws);
  // ---- ablation probes (T=64, outputs land in logits region, overwritten by head) ----
  hipLaunchKernelGGL(probe_kernel<0>, dim3(128), dim3(256), 0, stream,
                     ws + WBASE, ws, (ushort*)out, dones, astate, cstate,
                     abih, abhh, cbih, cbhh, out + POFF_);
  hipLaunchKernelGGL(probe_kernel<1>, dim3(128), dim3(256), 0, stream,
                     ws + WBASE, ws, (ushort*)out, dones, astate, cstate,
                     abih, abhh, cbih, cbhh, out + POFF_);
  hipLaunchKernelGGL(probe_kernel<2>, dim3(128), dim3(256), 0, stream,
                     ws + WBASE, ws, (ushort*)out, dones, astate, cstate,
                     abih, abhh, cbih, cbhh, out + POFF_);
  hipLaunchKernelGGL(probe_kernel<3>, dim3(128), dim3(256), 0, stream,
                     ws + WBASE, ws, (ushort*)out, dones, astate, cstate,
                     abih, abhh, cbih, cbhh, out + POFF_);
  // ---- real scan + heads ----
  hipLaunchKernelGGL(scan_kernel, dim3(128), dim3(256), 0, stream,
                     ws + WBASE, ws, ws, dones, astate, cstate,
                     abih, abhh, cbih, cbhh, out);
  hipLaunchKernelGGL(head_kernel, dim3(TB_ / 64), dim3(256), 0, stream,
                     ws, abl, cbv, out);
}

// Round 8
// 465.256 us; speedup vs baseline: 1.3668x; 1.3046x over previous
//
#include <hip/hip_runtime.h>
#include <hip/hip_bf16.h>

typedef short short8 __attribute__((ext_vector_type(8)));
typedef float f32x4 __attribute__((ext_vector_type(4)));

#define T_ 512
#define B_ 1024
#define D_ 128
#define H_ 64
#define A_ 18
#define TB_ (T_*B_)

// ws layout (ushort units): [x_actor | x_critic | bf16 weights]
#define XELEMS (TB_*H_)          // 33554432 per branch
#define WBASE  (2*XELEMS)
#define WBR    38912             // per-branch weight elems
#define W1OFF  0
#define W2OFF  8192
#define WIHOFF 12288
#define WHHOFF 24576
#define WHDOFF 36864

// out layout (floats): logits | values | actor_state | critic_state
#define LOGN  (TB_*A_)           // 9437184
#define VOFF_ LOGN
#define SOFF_ (LOGN + TB_)       // 9961472

#define S1_ (-1.4426950408889634f)   // -log2(e)   (r,z gates)
#define S2_ (-2.885390081777927f)    // -2*log2(e) (n gate)

__device__ __forceinline__ ushort f2bf(float f) {
  __hip_bfloat16 h = __float2bfloat16(f);
  return __builtin_bit_cast(ushort, h);
}
__device__ __forceinline__ uint cvt_pk_bf16(float lo, float hi) {
  uint r;
  asm("v_cvt_pk_bf16_f32 %0, %1, %2" : "=v"(r) : "v"(lo), "v"(hi));
  return r;
}
__device__ __forceinline__ f32x4 mfma16(short8 a, short8 b, f32x4 c) {
  return __builtin_amdgcn_mfma_f32_16x16x32_bf16(a, b, c, 0, 0, 0);
}

__global__ __launch_bounds__(256) void prep_kernel(
    const float* aW1, const float* aW2, const float* aWih, const float* aWhh, const float* aWl,
    const float* cW1, const float* cW2, const float* cWih, const float* cWhh, const float* cWv,
    ushort* wts) {
  int idx = blockIdx.x * 256 + threadIdx.x;
  if (idx >= 2*WBR) return;
  int br = idx / WBR, off = idx % WBR;
  float v;
  if      (off < W2OFF)  v = (br ? cW1  : aW1 )[off];
  else if (off < WIHOFF) v = (br ? cW2  : aW2 )[off - W2OFF];
  else if (off < WHHOFF) {
    int rel = off - WIHOFF;
    v = (br ? cWih : aWih)[rel];
    v *= (rel < 128*H_) ? S1_ : S2_;      // fold gate logistic scales
  }
  else if (off < WHDOFF) {
    int rel = off - WHHOFF;
    v = (br ? cWhh : aWhh)[rel];
    v *= (rel < 128*H_) ? S1_ : S2_;
  }
  else {
    int t = off - WHDOFF;
    if (br == 0) v = (t < A_*H_) ? aWl[t] : 0.f;
    else         v = (t < H_)    ? cWv[t] : 0.f;
  }
  wts[WBASE + idx] = f2bf(v);
}

// ---------------- phase 1: fused MLP, barrier-free, x -> ws (bf16, PLAIN row-major) ---
__global__ __launch_bounds__(256) void mlp_kernel(
    const float* __restrict__ obs, const ushort* __restrict__ wts,
    const float* __restrict__ ab1, const float* __restrict__ ab2,
    const float* __restrict__ cb1, const float* __restrict__ cb2,
    ushort* __restrict__ xout) {
  __shared__ __align__(16) ushort obsb[4][16 * D_];   // per-wave 4KB staged obs (bf16)
  __shared__ __align__(16) ushort htmp[4][16 * H_];   // per-wave 2KB, wave-local only
  const int tid = threadIdx.x;
  const int l = tid & 63, w = tid >> 6;
  const int lr = l & 15, lg = l >> 4;
  const int key = lr & 7;
  const long r0 = (long)blockIdx.x * 64;
  const f32x4 fzero = {0.f, 0.f, 0.f, 0.f};

  // stage this wave's 16 obs rows: fully-coalesced f32 loads -> cvt -> swizzled LDS
  {
    const float* src = obs + (r0 + (long)w * 16) * D_;
    #pragma unroll
    for (int i = 0; i < 8; ++i) {
      int ri = i * 2 + (l >> 5);          // row 0..15
      int cq = (l & 31) * 4;              // f32 col
      float4 v = *(const float4*)(src + ri * D_ + cq);
      uint lo = cvt_pk_bf16(v.x, v.y);
      uint hi = cvt_pk_bf16(v.z, v.w);
      int ch = (l & 31) >> 1;             // 16B chunk 0..15
      int chs = (ch & 8) | ((ch & 7) ^ (ri & 7));
      *(uint2*)(&obsb[w][ri * D_ + chs * 8 + (l & 1) * 4]) = uint2{lo, hi};
    }
  }
  short8 af[4];
  #pragma unroll
  for (int ks = 0; ks < 4; ++ks) {
    int ch = ks * 4 + lg;
    int chs = (ch & 8) | ((ch & 7) ^ (lr & 7));
    af[ks] = *(const short8*)(&obsb[w][lr * D_ + chs * 8]);
  }

  #pragma unroll 1
  for (int br = 0; br < 2; ++br) {
    const ushort* wb = wts + WBASE + br * WBR;
    const float* b1 = br ? cb1 : ab1;
    const float* b2 = br ? cb2 : ab2;

    f32x4 acc[4];
    #pragma unroll
    for (int nt = 0; nt < 4; ++nt) acc[nt] = fzero;
    #pragma unroll
    for (int ks = 0; ks < 4; ++ks) {
      #pragma unroll
      for (int nt = 0; nt < 4; ++nt) {
        int n = nt * 16 + lr;
        short8 b = *(const short8*)(wb + W1OFF + n * D_ + ks * 32 + lg * 8);
        acc[nt] = mfma16(af[ks], b, acc[nt]);
      }
    }
    #pragma unroll
    for (int nt = 0; nt < 4; ++nt) {
      int coln = nt * 16 + lr;
      float bias = b1[coln];
      #pragma unroll
      for (int j = 0; j < 4; ++j) {
        int rw = lg * 4 + j;
        float v = fmaxf(acc[nt][j] + bias, 0.f);
        int idx = rw * H_ + ((((coln >> 3) ^ (rw & 7))) << 3) + (coln & 7);
        htmp[w][idx] = f2bf(v);
      }
    }
    short8 a2[2];
    #pragma unroll
    for (int ks = 0; ks < 2; ++ks) {
      int c = ks * 4 + lg;
      a2[ks] = *(const short8*)(&htmp[w][lr * H_ + ((c ^ key) << 3)]);
    }
    f32x4 acc2[4];
    #pragma unroll
    for (int nt = 0; nt < 4; ++nt) acc2[nt] = fzero;
    #pragma unroll
    for (int ks = 0; ks < 2; ++ks) {
      #pragma unroll
      for (int nt = 0; nt < 4; ++nt) {
        int n = nt * 16 + lr;
        short8 b = *(const short8*)(wb + W2OFF + n * H_ + ks * 32 + lg * 8);
        acc2[nt] = mfma16(a2[ks], b, acc2[nt]);
      }
    }
    #pragma unroll
    for (int nt = 0; nt < 4; ++nt) {
      int coln = nt * 16 + lr;
      float bias = b2[coln];
      #pragma unroll
      for (int j = 0; j < 4; ++j) {
        int rw = lg * 4 + j;
        float v = fmaxf(acc2[nt][j] + bias, 0.f);
        int idx = rw * H_ + ((((coln >> 3) ^ (rw & 7))) << 3) + (coln & 7);
        htmp[w][idx] = f2bf(v);
      }
    }
    {
      ushort* dp = xout + (size_t)br * XELEMS + (size_t)(r0 + w * 16) * H_;
      #pragma unroll
      for (int i = 0; i < 2; ++i) {
        int id = l + i * 64;          // 128 chunks of 16B
        int rr = id >> 3, cc = id & 7;
        uint4 v = *(const uint4*)(&htmp[w][rr * H_ + ((cc ^ (rr & 7)) << 3)]);
        *(uint4*)(dp + rr * H_ + (cc << 3)) = v;
      }
    }
  }
}

// ---------------- phase 2: GRU scan, short-chain schedule ----------------------------
// Critical path per step: ds_read hf -> 2 chained hh-MFMAs (C preloaded with
// bias + ih·x) -> exp2/rcp gates -> cvt_pk -> ds_write -> barrier.
// x-side MFMAs (pre_{t+1}) + prefetch issue in the latency shadow.
__global__ __launch_bounds__(256, 1) void scan_kernel(
    const ushort* __restrict__ wts,     // ws + WBASE region
    const ushort* __restrict__ xin,     // ws x region (load-only view)
    ushort* __restrict__ hist,          // ws x region (store-only view; t-disjoint)
    const float* __restrict__ dones,
    const float* __restrict__ astate, const float* __restrict__ cstate,
    const float* __restrict__ abih, const float* __restrict__ abhh,
    const float* __restrict__ cbih, const float* __restrict__ cbhh,
    float* __restrict__ out) {
  __shared__ __align__(16) ushort hbuf[2][16 * H_];  // h^T tiles, 16B-unit swizzled
  __shared__ __align__(8)  ushort dl16[T_ * 16];     // done flags, 16KB
  const int tid = threadIdx.x;
  const int l = tid & 63, w = tid >> 6;
  const int lr = l & 15, lg = l >> 4;
  const int grp = blockIdx.x & 1;
  const int b0 = (blockIdx.x >> 1) * 16;

  const ushort* wb = wts + grp * WBR;
  const ushort* xp = xin + (size_t)grp * XELEMS;
  ushort* hp = hist + (size_t)grp * XELEMS;
  const float* bihp = grp ? cbih : abih;
  const float* bhhp = grp ? cbhh : abhh;
  const float* st   = grp ? cstate : astate;

  // dones -> LDS flags
  #pragma unroll
  for (int i = 0; i < 8; ++i) {
    int s = tid + i * 256;
    int t = s >> 2, p = s & 3;
    float4 v = *(const float4*)(dones + (size_t)t * B_ + b0 + p * 4);
    uint lo = (v.x != 0.f ? 1u : 0u) | ((v.y != 0.f ? 1u : 0u) << 16);
    uint hi = (v.z != 0.f ? 1u : 0u) | ((v.w != 0.f ? 1u : 0u) << 16);
    *(uint2*)(&dl16[t * 16 + p * 4]) = uint2{lo, hi};
  }

  short8 ihW[3][2], hhW[3][2];
  #pragma unroll
  for (int g = 0; g < 3; ++g) {
    int n = g * 64 + w * 16 + lr;
    #pragma unroll
    for (int ks = 0; ks < 2; ++ks) {
      ihW[g][ks] = *(const short8*)(wb + WIHOFF + n * H_ + ks * 32 + lg * 8);
      hhW[g][ks] = *(const short8*)(wb + WHHOFF + n * H_ + ks * 32 + lg * 8);
    }
  }

  const int o4 = w * 16 + lg * 4;
  f32x4 bs0, bs1, binv, bhnv;
  {
    float4 a0 = *(const float4*)(bihp + o4),       h0v = *(const float4*)(bhhp + o4);
    float4 a1 = *(const float4*)(bihp + 64 + o4),  h1v = *(const float4*)(bhhp + 64 + o4);
    float4 a2 = *(const float4*)(bihp + 128 + o4), h2v = *(const float4*)(bhhp + 128 + o4);
    bs0[0]=S1_*(a0.x+h0v.x); bs0[1]=S1_*(a0.y+h0v.y); bs0[2]=S1_*(a0.z+h0v.z); bs0[3]=S1_*(a0.w+h0v.w);
    bs1[0]=S1_*(a1.x+h1v.x); bs1[1]=S1_*(a1.y+h1v.y); bs1[2]=S1_*(a1.z+h1v.z); bs1[3]=S1_*(a1.w+h1v.w);
    binv[0]=S2_*a2.x; binv[1]=S2_*a2.y; binv[2]=S2_*a2.z; binv[3]=S2_*a2.w;
    bhnv[0]=S2_*h2v.x; bhnv[1]=S2_*h2v.y; bhnv[2]=S2_*h2v.z; bhnv[3]=S2_*h2v.w;
  }

  const int myW = lr * H_ + (((w * 2 + (lg >> 1)) ^ (lr & 7)) << 3) + (lg & 1) * 4;
  const int rdA = lr * H_ + (((0 + lg) ^ (lr & 7)) << 3);
  const int rdB = lr * H_ + (((4 + lg) ^ (lr & 7)) << 3);

  float h_old[4];
  {
    float4 h0v = *(const float4*)(st + (size_t)(b0 + lr) * H_ + o4);
    bool rs0 = (dones[b0 + lr] != 0.f);
    h_old[0] = rs0 ? 0.f : h0v.x; h_old[1] = rs0 ? 0.f : h0v.y;
    h_old[2] = rs0 ? 0.f : h0v.z; h_old[3] = rs0 ? 0.f : h0v.w;
    uint2 hv;
    hv.x = cvt_pk_bf16(h_old[0], h_old[1]);
    hv.y = cvt_pk_bf16(h_old[2], h_old[3]);
    *(uint2*)(&hbuf[0][myW]) = hv;
  }

  __syncthreads();

  auto loadx = [&](int t, short8 (&f)[2]) {
    const ushort* p = xp + ((size_t)t * B_ + b0 + lr) * H_;
    f[0] = *(const short8*)(p + lg * 8);
    f[1] = *(const short8*)(p + 32 + lg * 8);
  };

  short8 buf0[2], buf1[2], buf2[2], buf3[2];
  loadx(0, buf0); loadx(1, buf1); loadx(2, buf2); loadx(3, buf3);

  // pre[g] = bias + ih·x for the step about to run (x-side, h-independent)
  f32x4 preA[3], preB[3];
  auto cpre = [&](short8 (&xb)[2], f32x4 (&pre)[3]) {
    pre[0] = bs0;  pre[1] = bs1;  pre[2] = binv;
    pre[0] = mfma16(ihW[0][0], xb[0], pre[0]); pre[0] = mfma16(ihW[0][1], xb[1], pre[0]);
    pre[1] = mfma16(ihW[1][0], xb[0], pre[1]); pre[1] = mfma16(ihW[1][1], xb[1], pre[1]);
    pre[2] = mfma16(ihW[2][0], xb[0], pre[2]); pre[2] = mfma16(ihW[2][1], xb[1], pre[2]);
  };
  cpre(buf0, preA);

  int cur = 0;

  // xcur: buffer just consumed (gets t+4 prefetch); xnext: holds x_{t+1} for preN.
  auto dostep = [&](int t, short8 (&xcur)[2], short8 (&xnext)[2],
                    f32x4 (&preU)[3], f32x4 (&preN)[3]) {
    short8 hf0 = *(const short8*)(&hbuf[cur][rdA]);
    short8 hf1 = *(const short8*)(&hbuf[cur][rdB]);
    int tn = t + 1;
    ushort dn = dl16[((tn < T_) ? tn : 0) * 16 + lr];
    bool rs = (tn < T_) && (dn != 0);

    // critical path: 2 chained hh-MFMAs per gate (C = bias + ih·x, precomputed)
    f32x4 S0 = preU[0], S1 = preU[1], Gh = bhnv;
    S0 = mfma16(hhW[0][0], hf0, S0); S0 = mfma16(hhW[0][1], hf1, S0);
    S1 = mfma16(hhW[1][0], hf0, S1); S1 = mfma16(hhW[1][1], hf1, S1);
    Gh = mfma16(hhW[2][0], hf0, Gh); Gh = mfma16(hhW[2][1], hf1, Gh);

    // latency shadow: x-side MFMAs for t+1 and the t+4 prefetch
    cpre(xnext, preN);
    int tp = (t + 4 < T_) ? t + 4 : T_ - 1;
    loadx(tp, xcur);

    float hn[4];
    #pragma unroll
    for (int j = 0; j < 4; ++j) {
      float rr = __builtin_amdgcn_rcpf(1.f + __builtin_amdgcn_exp2f(S0[j]));
      float zz = __builtin_amdgcn_rcpf(1.f + __builtin_amdgcn_exp2f(S1[j]));
      float sn = fmaf(rr, Gh[j], preU[2][j]);
      float qq = __builtin_amdgcn_rcpf(1.f + __builtin_amdgcn_exp2f(sn));
      float nn = fmaf(2.f, qq, -1.f);
      hn[j] = fmaf(zz, h_old[j] - nn, nn);
    }
    uint2 hv;
    hv.x = cvt_pk_bf16(hn[0], hn[1]);
    hv.y = cvt_pk_bf16(hn[2], hn[3]);
    *(uint2*)(hp + ((size_t)t * B_ + b0 + lr) * H_ + o4) = hv;   // history (pre-reset)
    uint2 hz;
    hz.x = rs ? 0u : hv.x;
    hz.y = rs ? 0u : hv.y;
    h_old[0] = rs ? 0.f : hn[0]; h_old[1] = rs ? 0.f : hn[1];
    h_old[2] = rs ? 0.f : hn[2]; h_old[3] = rs ? 0.f : hn[3];
    int nxt = cur ^ 1;
    *(uint2*)(&hbuf[nxt][myW]) = hz;
    asm volatile("s_waitcnt lgkmcnt(0)" ::: "memory");
    __builtin_amdgcn_s_barrier();
    cur = nxt;
  };

  for (int it = 0; it < T_ / 4; ++it) {
    dostep(4 * it,     buf0, buf1, preA, preB);
    dostep(4 * it + 1, buf1, buf2, preB, preA);
    dostep(4 * it + 2, buf2, buf3, preA, preB);
    dostep(4 * it + 3, buf3, buf0, preB, preA);
  }

  // final states (fp32, post step 511; no reset applied on last step)
  float4 fs = {h_old[0], h_old[1], h_old[2], h_old[3]};
  *(float4*)(out + SOFF_ + (size_t)grp * (B_ * H_) + (size_t)(b0 + lr) * H_ + o4) = fs;
}

// ---------------- phase 3: heads (logits + values), LDS-staged coalesced stores -------
__global__ __launch_bounds__(256) void head_kernel(
    const ushort* __restrict__ ws,
    const float* __restrict__ abl, const float* __restrict__ cbv,
    float* __restrict__ out) {
  __shared__ float ltile[4][16 * A_];
  const int tid = threadIdx.x;
  const int l = tid & 63, w = tid >> 6;
  const int lr = l & 15, lg = l >> 4;
  const long r0 = (long)blockIdx.x * 64 + w * 16;
  const f32x4 fzero = {0.f, 0.f, 0.f, 0.f};

  const ushort* hA = ws + r0 * H_;
  const ushort* hC = ws + XELEMS + r0 * H_;
  short8 aA[2], aC[2];
  #pragma unroll
  for (int ks = 0; ks < 2; ++ks) {
    aA[ks] = *(const short8*)(hA + lr * H_ + ks * 32 + lg * 8);
    aC[ks] = *(const short8*)(hC + lr * H_ + ks * 32 + lg * 8);
  }
  const ushort* wbA = ws + WBASE + WHDOFF;
  const ushort* wbC = ws + WBASE + WBR + WHDOFF;
  f32x4 acc[2];
  acc[0] = fzero; acc[1] = fzero;
  #pragma unroll
  for (int nt = 0; nt < 2; ++nt) {
    int n = nt * 16 + lr;
    #pragma unroll
    for (int ks = 0; ks < 2; ++ks) {
      short8 b = *(const short8*)(wbA + n * H_ + ks * 32 + lg * 8);
      acc[nt] = mfma16(aA[ks], b, acc[nt]);
    }
  }
  f32x4 vacc = fzero;
  {
    int n = lr;
    #pragma unroll
    for (int ks = 0; ks < 2; ++ks) {
      short8 b = *(const short8*)(wbC + n * H_ + ks * 32 + lg * 8);
      vacc = mfma16(aC[ks], b, vacc);
    }
  }
  #pragma unroll
  for (int nt = 0; nt < 2; ++nt) {
    int n = nt * 16 + lr;
    if (n < A_) {
      float bias = abl[n];
      #pragma unroll
      for (int j = 0; j < 4; ++j)
        ltile[w][(lg * 4 + j) * A_ + n] = acc[nt][j] + bias;
    }
  }
  asm volatile("s_waitcnt lgkmcnt(0)" ::: "memory");
  #pragma unroll
  for (int i = 0; i < 5; ++i) {
    int idx = l + i * 64;
    if (idx < 16 * A_)
      out[r0 * A_ + idx] = ltile[w][idx];
  }
  if (lr == 0) {
    float bias = cbv[0];
    #pragma unroll
    for (int j = 0; j < 4; ++j)
      out[VOFF_ + r0 + lg * 4 + j] = vacc[j] + bias;
  }
}

extern "C" void kernel_launch(void* const* d_in, const int* in_sizes, int n_in,
                              void* d_out, int out_size, void* d_ws, size_t ws_size,
                              hipStream_t stream) {
  const float* obs    = (const float*)d_in[0];
  const float* dones  = (const float*)d_in[1];
  const float* astate = (const float*)d_in[2];
  const float* cstate = (const float*)d_in[3];
  const float* aW1  = (const float*)d_in[4];
  const float* ab1  = (const float*)d_in[5];
  const float* aW2  = (const float*)d_in[6];
  const float* ab2  = (const float*)d_in[7];
  const float* aWih = (const float*)d_in[8];
  const float* aWhh = (const float*)d_in[9];
  const float* abih = (const float*)d_in[10];
  const float* abhh = (const float*)d_in[11];
  const float* aWl  = (const float*)d_in[12];
  const float* abl  = (const float*)d_in[13];
  const float* cW1  = (const float*)d_in[14];
  const float* cb1  = (const float*)d_in[15];
  const float* cW2  = (const float*)d_in[16];
  const float* cb2  = (const float*)d_in[17];
  const float* cWih = (const float*)d_in[18];
  const float* cWhh = (const float*)d_in[19];
  const float* cbih = (const float*)d_in[20];
  const float* cbhh = (const float*)d_in[21];
  const float* cWv  = (const float*)d_in[22];
  const float* cbv  = (const float*)d_in[23];
  ushort* ws = (ushort*)d_ws;
  float* out = (float*)d_out;

  const size_t need = ((size_t)2 * XELEMS + 2 * WBR) * 2;
  if (ws_size < need) {
    hipMemsetAsync(d_out, 0x7F, 16, stream);
    return;
  }

  hipLaunchKernelGGL(prep_kernel, dim3(304), dim3(256), 0, stream,
                     aW1, aW2, aWih, aWhh, aWl, cW1, cW2, cWih, cWhh, cWv, ws);
  hipLaunchKernelGGL(mlp_kernel, dim3(TB_ / 64), dim3(256), 0, stream,
                     obs, ws, ab1, ab2, cb1, cb2, ws);
  hipLaunchKernelGGL(scan_kernel, dim3(128), dim3(256), 0, stream,
                     ws + WBASE, ws, ws, dones, astate, cstate,
                     abih, abhh, cbih, cbhh, out);
  hipLaunchKernelGGL(head_kernel, dim3(TB_ / 64), dim3(256), 0, stream,
                     ws, abl, cbv, out);
}